// Round 1
// baseline (1042.101 us; speedup 1.0000x reference)
//
#include <hip/hip_runtime.h>

#define N_NODES 50000
#define N_EDGES 800000

__device__ __forceinline__ float fast_tanh(float x) {
  // exact algebra: tanh(x) = 1 - 2/(exp(2x)+1); handles +-inf saturation correctly
  float e = __expf(2.0f * x);
  return 1.0f - 2.0f / (e + 1.0f);
}

// ---------- prep1: W12 = pi_W1 @ pi_W2  [128x64]; b12 = pi_b1 @ pi_W2 + pi_b2 [64]
__global__ __launch_bounds__(256) void prep1_kernel(
    const float* __restrict__ piW1, const float* __restrict__ pib1,
    const float* __restrict__ piW2, const float* __restrict__ pib2,
    float* __restrict__ W12, float* __restrict__ b12) {
  int gid = blockIdx.x * 256 + threadIdx.x;
  if (gid < 128 * 64) {
    int m = gid >> 6, c = gid & 63;
    float acc = 0.f;
    #pragma unroll 8
    for (int k = 0; k < 64; ++k) acc = fmaf(piW1[m * 64 + k], piW2[k * 64 + c], acc);
    W12[gid] = acc;
  } else if (gid < 128 * 64 + 64) {
    int c = gid - 128 * 64;
    float acc = pib2[c];
    for (int k = 0; k < 64; ++k) acc = fmaf(pib1[k], piW2[k * 64 + c], acc);
    b12[c] = acc;
  }
}

// ---------- prep2: W3i[k*8+b][c] = sum_m pi_W3[k][m*8+b] * ii_W1[m][c]   [512x64]
__global__ __launch_bounds__(256) void prep2_kernel(
    const float* __restrict__ piW3, const float* __restrict__ iiW1,
    float* __restrict__ W3i) {
  int gid = blockIdx.x * 256 + threadIdx.x;  // 32768 total
  int kb = gid >> 6, c = gid & 63;
  int k = kb >> 3, b = kb & 7;
  float acc = 0.f;
  #pragma unroll 8
  for (int m = 0; m < 64; ++m)
    acc = fmaf(piW3[k * 512 + m * 8 + b], iiW1[m * 64 + c], acc);
  W3i[gid] = acc;
}

// ---------- node: p1 = tanh(p@ppW1+b1)@ppW2+b2 ; qa = p1@W12[0:64]; qb = p1@W12[64:128]
__global__ __launch_bounds__(256) void node_kernel(
    const float* __restrict__ p,
    const float* __restrict__ ppW1, const float* __restrict__ ppb1,
    const float* __restrict__ ppW2, const float* __restrict__ ppb2,
    const float* __restrict__ W12,
    float* __restrict__ qa, float* __restrict__ qb) {
  __shared__ float sW1[64 * 64];
  __shared__ float sW2[64 * 64];
  __shared__ float sW12[128 * 64];
  __shared__ float sb1[64], sb2[64];
  __shared__ float sX[4][8][64];
  int tid = threadIdx.x;
  for (int i = tid; i < 64 * 64; i += 256) { sW1[i] = ppW1[i]; sW2[i] = ppW2[i]; }
  for (int i = tid; i < 128 * 64; i += 256) sW12[i] = W12[i];
  if (tid < 64) { sb1[tid] = ppb1[tid]; sb2[tid] = ppb2[tid]; }
  __syncthreads();
  int wave = tid >> 6, lane = tid & 63;
  int rowbase = blockIdx.x * 32 + wave * 8;

  // stage 8 rows of p into this wave's LDS slab (float4-coalesced)
  float4* sXf4 = (float4*)&sX[wave][0][0];
  for (int t = lane; t < 128; t += 64) {
    int r = t >> 4, c4 = t & 15;
    int row = rowbase + r;
    float4 v = make_float4(0.f, 0.f, 0.f, 0.f);
    if (row < N_NODES) v = ((const float4*)p)[row * 16 + c4];
    sXf4[t] = v;
  }
  __syncthreads();

  // layer 1 (lane = output column)
  float h[8];
  #pragma unroll
  for (int r = 0; r < 8; ++r) h[r] = sb1[lane];
  for (int k = 0; k < 64; ++k) {
    float w = sW1[k * 64 + lane];
    #pragma unroll
    for (int r = 0; r < 8; ++r) h[r] = fmaf(sX[wave][r][k], w, h[r]);
  }
  #pragma unroll
  for (int r = 0; r < 8; ++r) h[r] = fast_tanh(h[r]);
  __syncthreads();
  #pragma unroll
  for (int r = 0; r < 8; ++r) sX[wave][r][lane] = h[r];
  __syncthreads();

  // layer 2
  float g[8];
  #pragma unroll
  for (int r = 0; r < 8; ++r) g[r] = sb2[lane];
  for (int k = 0; k < 64; ++k) {
    float w = sW2[k * 64 + lane];
    #pragma unroll
    for (int r = 0; r < 8; ++r) g[r] = fmaf(sX[wave][r][k], w, g[r]);
  }
  __syncthreads();
  #pragma unroll
  for (int r = 0; r < 8; ++r) sX[wave][r][lane] = g[r];
  __syncthreads();

  // qa / qb (fused: read p1 value once, two weight columns)
  float a[8], b[8];
  #pragma unroll
  for (int r = 0; r < 8; ++r) { a[r] = 0.f; b[r] = 0.f; }
  for (int k = 0; k < 64; ++k) {
    float wa = sW12[k * 64 + lane];
    float wb = sW12[(64 + k) * 64 + lane];
    #pragma unroll
    for (int r = 0; r < 8; ++r) {
      float x = sX[wave][r][k];
      a[r] = fmaf(x, wa, a[r]);
      b[r] = fmaf(x, wb, b[r]);
    }
  }
  #pragma unroll
  for (int r = 0; r < 8; ++r) {
    int row = rowbase + r;
    if (row < N_NODES) {
      qa[row * 64 + lane] = a[r];
      qb[row * 64 + lane] = b[r];
    }
  }
}

// ---------- edge: h2 = qa[i]+qb[j]+b12 ; s = (h2 (x) basis) @ W3i + ii_b1 ;
//                  i2 = tanh(s) @ ii_W2 + ii_b2 ; out[idx_j] += i2 (atomic)
__global__ __launch_bounds__(256) void edge_kernel(
    const int* __restrict__ idx_i, const int* __restrict__ idx_j,
    const float* __restrict__ basis,
    const float* __restrict__ qa, const float* __restrict__ qb,
    const float* __restrict__ b12, const float* __restrict__ W3i,
    const float* __restrict__ iib1, const float* __restrict__ iiW2,
    const float* __restrict__ iib2, float* __restrict__ out) {
  __shared__ float sH2[64][68];     // 68 = 64 + 4 pad: breaks 4-way bank conflict on column reads
  __shared__ float sBasis[64][8];
  __shared__ float sW2[64 * 64];
  __shared__ int sII[64];
  __shared__ int sJJ[64];
  int tid = threadIdx.x;
  int e0 = blockIdx.x * 64;

  if (tid < 64) sII[tid] = idx_i[e0 + tid];
  else if (tid < 128) sJJ[tid - 64] = idx_j[e0 + (tid - 64)];
  else {
    int t = tid - 128;                       // 128 threads x 1 float4 = 512 floats
    ((float4*)sBasis)[t] = ((const float4*)basis)[e0 * 2 + t];
  }
  for (int t = tid; t < 1024; t += 256)
    ((float4*)sW2)[t] = ((const float4*)iiW2)[t];
  __syncthreads();

  // gather + add: h2 tile [64 edges][64]
  for (int t = tid; t < 1024; t += 256) {
    int e = t >> 4, q = t & 15;
    int ii = sII[e], jj = sJJ[e];
    float4 va = ((const float4*)qa)[ii * 16 + q];
    float4 vb = ((const float4*)qb)[jj * 16 + q];
    float4 vc = ((const float4*)b12)[q];
    float4 h = make_float4(va.x + vb.x + vc.x, va.y + vb.y + vc.y,
                           va.z + vb.z + vc.z, va.w + vb.w + vc.w);
    ((float4*)&sH2[e][0])[q] = h;
  }
  __syncthreads();

  int wave = tid >> 6, lane = tid & 63;
  int eg = lane >> 4, cg = lane & 15;      // 4 edge-groups x 16 col-groups per wave
  int eb = wave * 16 + eg * 4;             // this lane's 4 edges
  int c0 = cg * 4;                         // this lane's 4 columns

  float br[4][8];
  #pragma unroll
  for (int e = 0; e < 4; ++e)
    #pragma unroll
    for (int b = 0; b < 8; ++b) br[e][b] = sBasis[eb + e][b];

  float4 acc[4];
  float4 binit = ((const float4*)iib1)[cg];
  #pragma unroll
  for (int e = 0; e < 4; ++e) acc[e] = binit;

  // K=512 GEMM: A built on the fly as h2[e][k]*basis[e][b]; B = W3i streamed from L2
  const float4* W34 = (const float4*)W3i;
  for (int k = 0; k < 64; ++k) {
    float h0 = sH2[eb + 0][k];
    float h1 = sH2[eb + 1][k];
    float h2 = sH2[eb + 2][k];
    float h3 = sH2[eb + 3][k];
    #pragma unroll
    for (int b = 0; b < 8; ++b) {
      float4 w = W34[(k * 8 + b) * 16 + cg];
      float a0 = h0 * br[0][b];
      float a1 = h1 * br[1][b];
      float a2 = h2 * br[2][b];
      float a3 = h3 * br[3][b];
      acc[0].x = fmaf(a0, w.x, acc[0].x); acc[0].y = fmaf(a0, w.y, acc[0].y);
      acc[0].z = fmaf(a0, w.z, acc[0].z); acc[0].w = fmaf(a0, w.w, acc[0].w);
      acc[1].x = fmaf(a1, w.x, acc[1].x); acc[1].y = fmaf(a1, w.y, acc[1].y);
      acc[1].z = fmaf(a1, w.z, acc[1].z); acc[1].w = fmaf(a1, w.w, acc[1].w);
      acc[2].x = fmaf(a2, w.x, acc[2].x); acc[2].y = fmaf(a2, w.y, acc[2].y);
      acc[2].z = fmaf(a2, w.z, acc[2].z); acc[2].w = fmaf(a2, w.w, acc[2].w);
      acc[3].x = fmaf(a3, w.x, acc[3].x); acc[3].y = fmaf(a3, w.y, acc[3].y);
      acc[3].z = fmaf(a3, w.z, acc[3].z); acc[3].w = fmaf(a3, w.w, acc[3].w);
    }
  }

  // tanh, write t back into sH2 (each wave touches only its own 16 rows)
  #pragma unroll
  for (int e = 0; e < 4; ++e) {
    float4 t;
    t.x = fast_tanh(acc[e].x);
    t.y = fast_tanh(acc[e].y);
    t.z = fast_tanh(acc[e].z);
    t.w = fast_tanh(acc[e].w);
    ((float4*)&sH2[eb + e][0])[cg] = t;
  }
  __syncthreads();

  // K=64 GEMM with ii_W2
  float4 acc2[4];
  float4 b2v = ((const float4*)iib2)[cg];
  #pragma unroll
  for (int e = 0; e < 4; ++e) acc2[e] = b2v;
  for (int k = 0; k < 64; ++k) {
    float4 w = ((const float4*)sW2)[k * 16 + cg];
    #pragma unroll
    for (int e = 0; e < 4; ++e) {
      float x = sH2[eb + e][k];
      acc2[e].x = fmaf(x, w.x, acc2[e].x);
      acc2[e].y = fmaf(x, w.y, acc2[e].y);
      acc2[e].z = fmaf(x, w.z, acc2[e].z);
      acc2[e].w = fmaf(x, w.w, acc2[e].w);
    }
  }

  // scatter-add by idx_j
  #pragma unroll
  for (int e = 0; e < 4; ++e) {
    int jj = sJJ[wave * 16 + eg * 4 + e];
    float* po = &out[jj * 64 + c0];
    atomicAdd(po + 0, acc2[e].x);
    atomicAdd(po + 1, acc2[e].y);
    atomicAdd(po + 2, acc2[e].z);
    atomicAdd(po + 3, acc2[e].w);
  }
}

extern "C" void kernel_launch(void* const* d_in, const int* in_sizes, int n_in,
                              void* d_out, int out_size, void* d_ws, size_t ws_size,
                              hipStream_t stream) {
  const float* p     = (const float*)d_in[0];
  const int*   idx_i = (const int*)d_in[1];
  const int*   idx_j = (const int*)d_in[2];
  const float* basis = (const float*)d_in[3];
  const float* ppW1  = (const float*)d_in[4];
  const float* ppb1  = (const float*)d_in[5];
  const float* ppW2  = (const float*)d_in[6];
  const float* ppb2  = (const float*)d_in[7];
  const float* piW1  = (const float*)d_in[8];
  const float* pib1  = (const float*)d_in[9];
  const float* piW2  = (const float*)d_in[10];
  const float* pib2  = (const float*)d_in[11];
  const float* piW3  = (const float*)d_in[12];
  const float* iiW1  = (const float*)d_in[13];
  const float* iib1  = (const float*)d_in[14];
  const float* iiW2  = (const float*)d_in[15];
  const float* iib2  = (const float*)d_in[16];

  float* ws  = (float*)d_ws;
  float* qa  = ws;                 // 50000*64 = 3,200,000 floats
  float* qb  = ws + 3200000;       // 3,200,000 floats
  float* W12 = ws + 6400000;       // 128*64 = 8192
  float* b12 = ws + 6408192;       // 64
  float* W3i = ws + 6408256;       // 512*64 = 32768   (total ~25.8 MB)

  hipMemsetAsync(d_out, 0, (size_t)out_size * sizeof(float), stream);
  prep1_kernel<<<33, 256, 0, stream>>>(piW1, pib1, piW2, pib2, W12, b12);
  prep2_kernel<<<128, 256, 0, stream>>>(piW3, iiW1, W3i);
  node_kernel<<<1563, 256, 0, stream>>>(p, ppW1, ppb1, ppW2, ppb2, W12, qa, qb);
  edge_kernel<<<12500, 256, 0, stream>>>(idx_i, idx_j, basis, qa, qb, b12, W3i,
                                         iib1, iiW2, iib2, (float*)d_out);
}

// Round 2
// 291.138 us; speedup vs baseline: 3.5794x; 3.5794x over previous
//
#include <hip/hip_runtime.h>

#define N_NODES 50000
#define N_EDGES 800000

typedef float f32x4 __attribute__((ext_vector_type(4)));
typedef short bf16x8 __attribute__((ext_vector_type(8)));

__device__ __forceinline__ float fast_tanh(float x) {
  // exact algebra: tanh(x) = 1 - 2/(exp(2x)+1)
  float e = __expf(2.0f * x);
  return 1.0f - 2.0f / (e + 1.0f);
}

__device__ __forceinline__ unsigned short f2bf_rne(float x) {
  unsigned u = __float_as_uint(x);
  unsigned r = u + 0x7FFFu + ((u >> 16) & 1u);
  return (unsigned short)(r >> 16);
}

// ---------- prep1: W12 = pi_W1 @ pi_W2  [128x64]; b12 = pi_b1 @ pi_W2 + pi_b2 [64]
__global__ __launch_bounds__(256) void prep1_kernel(
    const float* __restrict__ piW1, const float* __restrict__ pib1,
    const float* __restrict__ piW2, const float* __restrict__ pib2,
    float* __restrict__ W12, float* __restrict__ b12) {
  int gid = blockIdx.x * 256 + threadIdx.x;
  if (gid < 128 * 64) {
    int m = gid >> 6, c = gid & 63;
    float acc = 0.f;
    #pragma unroll 8
    for (int k = 0; k < 64; ++k) acc = fmaf(piW1[m * 64 + k], piW2[k * 64 + c], acc);
    W12[gid] = acc;
  } else if (gid < 128 * 64 + 64) {
    int c = gid - 128 * 64;
    float acc = pib2[c];
    for (int k = 0; k < 64; ++k) acc = fmaf(pib1[k], piW2[k * 64 + c], acc);
    b12[c] = acc;
  }
}

// ---------- prep_b: Bpack[ks][ct][lane][j] = bf16( W3i[kidx][col] )
// W3i[kidx][c] = sum_m piW3[k][m*8+b]*iiW1[m][c], kidx=k*8+b
// kidx = ks*32 + (lane>>4)*8 + j ; col = ct*16 + (lane&15)
__global__ __launch_bounds__(256) void prep_b_kernel(
    const float* __restrict__ piW3, const float* __restrict__ iiW1,
    unsigned short* __restrict__ Bpack) {
  int gid = blockIdx.x * 256 + threadIdx.x;  // 32768 total
  int j = gid & 7;
  int lane = (gid >> 3) & 63;
  int ct = (gid >> 9) & 3;
  int ks = gid >> 11;
  int kidx = ks * 32 + ((lane >> 4) << 3) + j;
  int col = ct * 16 + (lane & 15);
  int k = kidx >> 3, b = kidx & 7;
  float acc = 0.f;
  #pragma unroll 8
  for (int mm = 0; mm < 64; ++mm)
    acc = fmaf(piW3[k * 512 + mm * 8 + b], iiW1[mm * 64 + col], acc);
  Bpack[gid] = f2bf_rne(acc);
}

// ---------- prep_w2: W2pack[ks][ct][lane][j] = bf16( iiW2[kidx][col] )
__global__ __launch_bounds__(256) void prep_w2_kernel(
    const float* __restrict__ iiW2, unsigned short* __restrict__ W2pack) {
  int gid = blockIdx.x * 256 + threadIdx.x;  // 4096 total
  int j = gid & 7;
  int lane = (gid >> 3) & 63;
  int ct = (gid >> 9) & 3;
  int ks = gid >> 11;
  int kidx = ks * 32 + ((lane >> 4) << 3) + j;
  int col = ct * 16 + (lane & 15);
  W2pack[gid] = f2bf_rne(iiW2[kidx * 64 + col]);
}

// ---------- node: p1 = tanh(p@ppW1+b1)@ppW2+b2 ; qa = p1@W12[0:64]; qb = p1@W12[64:128]
__global__ __launch_bounds__(256) void node_kernel(
    const float* __restrict__ p,
    const float* __restrict__ ppW1, const float* __restrict__ ppb1,
    const float* __restrict__ ppW2, const float* __restrict__ ppb2,
    const float* __restrict__ W12,
    float* __restrict__ qa, float* __restrict__ qb) {
  __shared__ float sW1[64 * 64];
  __shared__ float sW2[64 * 64];
  __shared__ float sW12[128 * 64];
  __shared__ float sb1[64], sb2[64];
  __shared__ float sX[4][8][64];
  int tid = threadIdx.x;
  for (int i = tid; i < 64 * 64; i += 256) { sW1[i] = ppW1[i]; sW2[i] = ppW2[i]; }
  for (int i = tid; i < 128 * 64; i += 256) sW12[i] = W12[i];
  if (tid < 64) { sb1[tid] = ppb1[tid]; sb2[tid] = ppb2[tid]; }
  __syncthreads();
  int wave = tid >> 6, lane = tid & 63;
  int rowbase = blockIdx.x * 32 + wave * 8;

  float4* sXf4 = (float4*)&sX[wave][0][0];
  for (int t = lane; t < 128; t += 64) {
    int r = t >> 4, c4 = t & 15;
    int row = rowbase + r;
    float4 v = make_float4(0.f, 0.f, 0.f, 0.f);
    if (row < N_NODES) v = ((const float4*)p)[row * 16 + c4];
    sXf4[t] = v;
  }
  __syncthreads();

  float h[8];
  #pragma unroll
  for (int r = 0; r < 8; ++r) h[r] = sb1[lane];
  for (int k = 0; k < 64; ++k) {
    float w = sW1[k * 64 + lane];
    #pragma unroll
    for (int r = 0; r < 8; ++r) h[r] = fmaf(sX[wave][r][k], w, h[r]);
  }
  #pragma unroll
  for (int r = 0; r < 8; ++r) h[r] = fast_tanh(h[r]);
  __syncthreads();
  #pragma unroll
  for (int r = 0; r < 8; ++r) sX[wave][r][lane] = h[r];
  __syncthreads();

  float g[8];
  #pragma unroll
  for (int r = 0; r < 8; ++r) g[r] = sb2[lane];
  for (int k = 0; k < 64; ++k) {
    float w = sW2[k * 64 + lane];
    #pragma unroll
    for (int r = 0; r < 8; ++r) g[r] = fmaf(sX[wave][r][k], w, g[r]);
  }
  __syncthreads();
  #pragma unroll
  for (int r = 0; r < 8; ++r) sX[wave][r][lane] = g[r];
  __syncthreads();

  float a[8], b[8];
  #pragma unroll
  for (int r = 0; r < 8; ++r) { a[r] = 0.f; b[r] = 0.f; }
  for (int k = 0; k < 64; ++k) {
    float wa = sW12[k * 64 + lane];
    float wb = sW12[(64 + k) * 64 + lane];
    #pragma unroll
    for (int r = 0; r < 8; ++r) {
      float x = sX[wave][r][k];
      a[r] = fmaf(x, wa, a[r]);
      b[r] = fmaf(x, wb, b[r]);
    }
  }
  #pragma unroll
  for (int r = 0; r < 8; ++r) {
    int row = rowbase + r;
    if (row < N_NODES) {
      qa[row * 64 + lane] = a[r];
      qb[row * 64 + lane] = b[r];
    }
  }
}

// ---------- edge: h2 = qa[i]+qb[j]+b12 ; s = (h2 (x) basis) @ W3i + ii_b1 (MFMA, split-A bf16)
//                  t = tanh(s) ; i2 = t @ ii_W2 + ii_b2 (MFMA) ; out[idx_j] += i2 (atomic)
__global__ __launch_bounds__(512, 4) void edge_kernel(
    const int* __restrict__ idx_i, const int* __restrict__ idx_j,
    const float* __restrict__ basis,
    const float* __restrict__ qa, const float* __restrict__ qb,
    const float* __restrict__ b12,
    const unsigned short* __restrict__ Bpack,
    const unsigned short* __restrict__ W2pack,
    const float* __restrict__ iib1, const float* __restrict__ iib2,
    float* __restrict__ out) {
  // 64 KB LDS union: phase0 = h2 tile [128][68] f32 (34.8 KB)
  //                  phase1 = Bpack   [16][4][64][8] bf16 (64 KB)
  //                  phase2 = t tile  [128][72] bf16 (18 KB)
  __shared__ __align__(16) unsigned short sB[32768];
  float* sH2 = (float*)sB;
  unsigned short* sT = sB;

  int tid = threadIdx.x;
  int e0 = blockIdx.x * 128;

  // ---- phase 0: gather h2 into LDS (f32)
  for (int t = tid; t < 2048; t += 512) {
    int e = t >> 4, q = t & 15;
    int ii = idx_i[e0 + e];
    int jj = idx_j[e0 + e];
    float4 va = ((const float4*)qa)[ii * 16 + q];
    float4 vb = ((const float4*)qb)[jj * 16 + q];
    float4 vc = ((const float4*)b12)[q];
    float4 h;
    h.x = va.x + vb.x + vc.x;
    h.y = va.y + vb.y + vc.y;
    h.z = va.z + vb.z + vc.z;
    h.w = va.w + vb.w + vc.w;
    ((float4*)(sH2 + e * 68))[q] = h;
  }
  __syncthreads();

  int w = tid >> 6, l = tid & 63;
  int m = l & 15, s = l >> 4;
  int eloc = w * 16 + m;  // this lane's edge row (A-operand row = l&15)

  // per-lane A inputs into registers: h2[e][k] for k = 4*ks + s, and basis[e][0..8)
  float h2r[16];
  #pragma unroll
  for (int t = 0; t < 16; ++t) h2r[t] = sH2[eloc * 68 + t * 4 + s];

  float bas[8];
  {
    const float4* bp = (const float4*)(basis + (size_t)(e0 + eloc) * 8);
    float4 b0 = bp[0], b1 = bp[1];
    bas[0] = b0.x; bas[1] = b0.y; bas[2] = b0.z; bas[3] = b0.w;
    bas[4] = b1.x; bas[5] = b1.y; bas[6] = b1.z; bas[7] = b1.w;
  }
  __syncthreads();

  // ---- phase 1: stage Bpack (64 KB) into LDS
  {
    const uint4* g = (const uint4*)Bpack;
    uint4* d = (uint4*)sB;
    #pragma unroll
    for (int t = 0; t < 8; ++t) d[tid + t * 512] = g[tid + t * 512];
  }
  __syncthreads();

  // C init with ii_b1 (col = ct*16 + m, same for the 4 rows)
  f32x4 c0, c1, c2, c3;
  {
    float v0 = iib1[m], v1 = iib1[16 + m], v2 = iib1[32 + m], v3 = iib1[48 + m];
    c0 = (f32x4){v0, v0, v0, v0};
    c1 = (f32x4){v1, v1, v1, v1};
    c2 = (f32x4){v2, v2, v2, v2};
    c3 = (f32x4){v3, v3, v3, v3};
  }

  // ---- main K-loop: 16 K-steps x (4 col-tiles) x (hi+lo A) = 128 MFMA/wave
  const bf16x8* Bl = (const bf16x8*)sB;
  #pragma unroll
  for (int ks = 0; ks < 16; ++ks) {
    bf16x8 B0 = Bl[(ks * 4 + 0) * 64 + l];
    bf16x8 B1 = Bl[(ks * 4 + 1) * 64 + l];
    bf16x8 B2 = Bl[(ks * 4 + 2) * 64 + l];
    bf16x8 B3 = Bl[(ks * 4 + 3) * 64 + l];
    float hv = h2r[ks];
    union { unsigned u[4]; bf16x8 v; } Ah, Al;
    #pragma unroll
    for (int jj2 = 0; jj2 < 4; ++jj2) {
      float p0 = hv * bas[2 * jj2];
      float p1 = hv * bas[2 * jj2 + 1];
      unsigned u0 = __float_as_uint(p0), u1 = __float_as_uint(p1);
      unsigned h0 = u0 & 0xFFFF0000u, h1 = u1 & 0xFFFF0000u;
      Ah.u[jj2] = (u0 >> 16) | h1;                 // truncated-hi bf16 pair
      float l0 = p0 - __uint_as_float(h0);         // exact residual
      float l1 = p1 - __uint_as_float(h1);
      Al.u[jj2] = (__float_as_uint(l0) >> 16) | (__float_as_uint(l1) & 0xFFFF0000u);
    }
    c0 = __builtin_amdgcn_mfma_f32_16x16x32_bf16(Ah.v, B0, c0, 0, 0, 0);
    c1 = __builtin_amdgcn_mfma_f32_16x16x32_bf16(Ah.v, B1, c1, 0, 0, 0);
    c2 = __builtin_amdgcn_mfma_f32_16x16x32_bf16(Ah.v, B2, c2, 0, 0, 0);
    c3 = __builtin_amdgcn_mfma_f32_16x16x32_bf16(Ah.v, B3, c3, 0, 0, 0);
    c0 = __builtin_amdgcn_mfma_f32_16x16x32_bf16(Al.v, B0, c0, 0, 0, 0);
    c1 = __builtin_amdgcn_mfma_f32_16x16x32_bf16(Al.v, B1, c1, 0, 0, 0);
    c2 = __builtin_amdgcn_mfma_f32_16x16x32_bf16(Al.v, B2, c2, 0, 0, 0);
    c3 = __builtin_amdgcn_mfma_f32_16x16x32_bf16(Al.v, B3, c3, 0, 0, 0);
  }
  __syncthreads();  // all waves done reading Bpack region

  // ---- phase 2: tanh -> t tile (bf16, rows = this wave's 16 edges)
  // C/D layout: col = ct*16 + m, row(local) = s*4 + r
  #pragma unroll
  for (int r = 0; r < 4; ++r) {
    int row = w * 16 + s * 4 + r;
    sT[row * 72 + 0 * 16 + m] = f2bf_rne(fast_tanh(c0[r]));
    sT[row * 72 + 1 * 16 + m] = f2bf_rne(fast_tanh(c1[r]));
    sT[row * 72 + 2 * 16 + m] = f2bf_rne(fast_tanh(c2[r]));
    sT[row * 72 + 3 * 16 + m] = f2bf_rne(fast_tanh(c3[r]));
  }
  __syncthreads();

  // ---- second GEMM: i2 = t @ ii_W2 + ii_b2   (K=64: 2 K-steps x 4 col-tiles)
  f32x4 d0, d1, d2, d3;
  {
    float v0 = iib2[m], v1 = iib2[16 + m], v2 = iib2[32 + m], v3 = iib2[48 + m];
    d0 = (f32x4){v0, v0, v0, v0};
    d1 = (f32x4){v1, v1, v1, v1};
    d2 = (f32x4){v2, v2, v2, v2};
    d3 = (f32x4){v3, v3, v3, v3};
  }
  const bf16x8* Wl = (const bf16x8*)W2pack;
  #pragma unroll
  for (int ks = 0; ks < 2; ++ks) {
    bf16x8 Af = *(const bf16x8*)(sT + eloc * 72 + ks * 32 + s * 8);
    d0 = __builtin_amdgcn_mfma_f32_16x16x32_bf16(Af, Wl[(ks * 4 + 0) * 64 + l], d0, 0, 0, 0);
    d1 = __builtin_amdgcn_mfma_f32_16x16x32_bf16(Af, Wl[(ks * 4 + 1) * 64 + l], d1, 0, 0, 0);
    d2 = __builtin_amdgcn_mfma_f32_16x16x32_bf16(Af, Wl[(ks * 4 + 2) * 64 + l], d2, 0, 0, 0);
    d3 = __builtin_amdgcn_mfma_f32_16x16x32_bf16(Af, Wl[(ks * 4 + 3) * 64 + l], d3, 0, 0, 0);
  }

  // ---- scatter-add by idx_j (coalesced 16-lane bursts per row segment)
  #pragma unroll
  for (int r = 0; r < 4; ++r) {
    int jj = idx_j[e0 + w * 16 + s * 4 + r];
    float* po = out + (size_t)jj * 64;
    atomicAdd(po + m, d0[r]);
    atomicAdd(po + 16 + m, d1[r]);
    atomicAdd(po + 32 + m, d2[r]);
    atomicAdd(po + 48 + m, d3[r]);
  }
}

extern "C" void kernel_launch(void* const* d_in, const int* in_sizes, int n_in,
                              void* d_out, int out_size, void* d_ws, size_t ws_size,
                              hipStream_t stream) {
  const float* p     = (const float*)d_in[0];
  const int*   idx_i = (const int*)d_in[1];
  const int*   idx_j = (const int*)d_in[2];
  const float* basis = (const float*)d_in[3];
  const float* ppW1  = (const float*)d_in[4];
  const float* ppb1  = (const float*)d_in[5];
  const float* ppW2  = (const float*)d_in[6];
  const float* ppb2  = (const float*)d_in[7];
  const float* piW1  = (const float*)d_in[8];
  const float* pib1  = (const float*)d_in[9];
  const float* piW2  = (const float*)d_in[10];
  const float* pib2  = (const float*)d_in[11];
  const float* piW3  = (const float*)d_in[12];
  const float* iiW1  = (const float*)d_in[13];
  const float* iib1  = (const float*)d_in[14];
  const float* iiW2  = (const float*)d_in[15];
  const float* iib2  = (const float*)d_in[16];

  float* ws  = (float*)d_ws;
  float* qa  = ws;                         // 3,200,000 floats
  float* qb  = ws + 3200000;               // 3,200,000 floats
  float* W12 = ws + 6400000;               // 8192
  float* b12 = ws + 6408192;               // 64
  unsigned short* Bpack  = (unsigned short*)(ws + 6408256);          // 32768 bf16 (64 KB)
  unsigned short* W2pack = (unsigned short*)(ws + 6408256 + 16384);  // 4096 bf16 (8 KB)

  hipMemsetAsync(d_out, 0, (size_t)out_size * sizeof(float), stream);
  prep1_kernel<<<33, 256, 0, stream>>>(piW1, pib1, piW2, pib2, W12, b12);
  prep_b_kernel<<<128, 256, 0, stream>>>(piW3, iiW1, Bpack);
  prep_w2_kernel<<<16, 256, 0, stream>>>(iiW2, W2pack);
  node_kernel<<<1563, 256, 0, stream>>>(p, ppW1, ppb1, ppW2, ppb2, W12, qa, qb);
  edge_kernel<<<6250, 512, 0, stream>>>(idx_i, idx_j, basis, qa, qb, b12,
                                        Bpack, W2pack, iib1, iib2, (float*)d_out);
}